// Round 11
// baseline (1457.406 us; speedup 1.0000x reference)
//
#include <hip/hip_runtime.h>

// VQ-VAE fused forward, f32 throughout.
// Algebra: all 512-dim contractions folded into precomputed tables:
//   WC[k][c]  = enc_wf[k,:]·cb[c,:]          (P = rep·cb^T = h2@WC + bfc)
//   Gm[o][k]  = enc_wf[o,:]·enc_wf[k,:]      (||rep||^2 = h2^T Gm h2 + 2 u·h2 + bb)
//   Mdec[r][j]= cb[r,:]·dec_w1[:,j]          (dec h1 preact = b1d + sum_g Mdec[g*32+k_g])
//   Gram[ga,gb,ka,kb] = cb_ga[ka,:]·cb_gb[kb,:]  (residual dots across groups)
// R9 (resubmit x3; benches never ran - GPU acquisition timeouts):
// kill the lgkmcnt serialization. R6/R8 both pinned at VALUBusy~52%
// regardless of occupancy/spill: uniform (readfirstlane) weight bases emit
// s_load (SMEM), which shares lgkmcnt with ds_read and returns OUT-OF-ORDER
// -> every weight use forces lgkmcnt(0), draining ds prefetch. Fix: force the
// weight chunk base into a VGPR (asm "+v") so weight streams go through
// global_load (vmcnt). lgkm queue = pure in-order ds_read -> counted waits.
//   + 1024 thr, CH=8, __launch_bounds__(1024,4): budget 128, usage ~45<=64
//     -> 2 blk/CU x 16 waves = 32 waves/CU, no spill (R8-proven regime).
//   + fused P3, 16-lane P4, 4-chain ILP dot512 in k_pre.

#define SIN  90
#define HID  128
#define DLAT 512
#define NC   128
#define HST  132    // H row stride (dwords): %4==0 (b128 align), %32==4 (bank spread)

// ws float layout, after 8 doubles (64 bytes) of accumulators:
//   [0,16384)      WC
//   [16384,32768)  Gm
//   [32768,49152)  Mdec  (row = g*32+k, col j)
//   [49152,65536)  Gram  idx = ((ga*4+gb)*32+ka)*32+kb
//   [65536,65664)  cbn2[128]
//   [65664,65792)  u[128]      (wf·bf)
//   [65792,65920)  bfc[128]    (bf·cb_c)
//   [65920]        bb = ||bf||^2
#define PRE_N 65921

__device__ __forceinline__ float dot512(const float* __restrict__ a,
                                        const float* __restrict__ b) {
    const float4* a4 = (const float4*)a;
    const float4* b4 = (const float4*)b;
    float s0 = 0.f, s1 = 0.f, s2 = 0.f, s3 = 0.f;
    for (int d = 0; d < DLAT / 4; d += 4) {
        float4 av, bv;
        av = a4[d];     bv = b4[d];
        s0 = fmaf(av.x, bv.x, s0); s0 = fmaf(av.y, bv.y, s0);
        s0 = fmaf(av.z, bv.z, s0); s0 = fmaf(av.w, bv.w, s0);
        av = a4[d + 1]; bv = b4[d + 1];
        s1 = fmaf(av.x, bv.x, s1); s1 = fmaf(av.y, bv.y, s1);
        s1 = fmaf(av.z, bv.z, s1); s1 = fmaf(av.w, bv.w, s1);
        av = a4[d + 2]; bv = b4[d + 2];
        s2 = fmaf(av.x, bv.x, s2); s2 = fmaf(av.y, bv.y, s2);
        s2 = fmaf(av.z, bv.z, s2); s2 = fmaf(av.w, bv.w, s2);
        av = a4[d + 3]; bv = b4[d + 3];
        s3 = fmaf(av.x, bv.x, s3); s3 = fmaf(av.y, bv.y, s3);
        s3 = fmaf(av.z, bv.z, s3); s3 = fmaf(av.w, bv.w, s3);
    }
    return (s0 + s1) + (s2 + s3);
}

__global__ void k_pre(const float* __restrict__ wf, const float* __restrict__ bf,
                      const float* __restrict__ w1d, const float* __restrict__ cb,
                      float* __restrict__ P, double* __restrict__ acc) {
    int idx = blockIdx.x * 256 + threadIdx.x;
    if (idx < 4) acc[idx] = 0.0;          // folded k_zero
    if (idx >= PRE_N) return;
    float s = 0.f;
    if (idx < 16384) {
        int k = idx >> 7, c = idx & 127;
        s = dot512(wf + k * DLAT, cb + c * DLAT);
    } else if (idx < 32768) {
        int r = idx - 16384; int o = r >> 7, k = r & 127;
        s = dot512(wf + o * DLAT, wf + k * DLAT);
    } else if (idx < 49152) {
        int r = idx - 32768; int row = r >> 7, j = r & 127;
        const float* a = cb + row * DLAT;
        float t0 = 0.f, t1 = 0.f;
        for (int d = 0; d < DLAT; d += 2) {
            t0 = fmaf(a[d],     w1d[d * HID + j],       t0);
            t1 = fmaf(a[d + 1], w1d[(d + 1) * HID + j], t1);
        }
        s = t0 + t1;
    } else if (idx < 65536) {
        int r = idx - 49152;
        int kb = r & 31, ka = (r >> 5) & 31, gb = (r >> 10) & 3, ga = (r >> 12) & 3;
        s = dot512(cb + (ga * 32 + ka) * DLAT, cb + (gb * 32 + kb) * DLAT);
    } else if (idx < 65664) {
        int c = idx - 65536;
        s = dot512(cb + c * DLAT, cb + c * DLAT);
    } else if (idx < 65792) {
        int k = idx - 65664;
        s = dot512(wf + k * DLAT, bf);
    } else if (idx < 65920) {
        int c = idx - 65792;
        s = dot512(bf, cb + c * DLAT);
    } else {
        s = dot512(bf, bf);
    }
    P[idx] = s;
}

#define CH 8      // out dims per wave (16 waves x 8 = 128)
#define NW 16     // waves per block

__global__ __launch_bounds__(1024, 4) void k_main(
    const float* __restrict__ x,
    const float* __restrict__ w1, const float* __restrict__ b1,
    const float* __restrict__ w2, const float* __restrict__ b2,
    const float* __restrict__ b1d,
    const float* __restrict__ w2d, const float* __restrict__ b2d,
    const float* __restrict__ wfd, const float* __restrict__ bfd,
    const float* __restrict__ pre,
    float* __restrict__ out, double* __restrict__ acc, int Bn)
{
    __shared__ __align__(16) float H[64 * HST];
    __shared__ float qfb[NW * 64];
    __shared__ int   cbuf[4 * 64];
    __shared__ float red[3 * NW];

    const int t = threadIdx.x;
    const int lane = t & 63;
    const int wv = t >> 6;                                    // 0..15
    const int ob = __builtin_amdgcn_readfirstlane(wv) * CH;   // uniform chunk base (bias s_loads)

    // VGPR copy of the chunk base: weight addresses become divergent to the
    // compiler -> global_load (vmcnt), NOT s_load (lgkmcnt). Same-address
    // lanes broadcast from L1/L2. This unmixes lgkmcnt (pure ds_read).
    int obv = wv * CH;
    asm volatile("" : "+v"(obv));

    const float* WC   = pre;
    const float* Gm   = pre + 16384;
    const float* Mdec = pre + 32768;
    const float* Gram = pre + 49152;
    const float* cbn2 = pre + 65536;
    const float* uu   = pre + 65664;
    const float* bfc  = pre + 65792;
    const float  bb   = pre[65920];

    const float4* hr = (const float4*)(H + lane * HST);   // own row, b128 stream
    float4*       hw = (float4*)(H + lane * HST + ob);    // own row, own chunk

    float a[CH];

    // ---- P0: stage x tile -> H[s][0..89] (coalesced global reads)
    {
        const float* xb = x + (long)blockIdx.x * 64 * SIN;
        for (int i = t; i < 64 * SIN; i += 1024) {
            int s = i / SIN;
            int k = i - s * SIN;
            H[s * HST + k] = xb[i];
        }
    }
    __syncthreads();

    // ---- P1: enc h1 = relu(x@w1 + b1); read own row (x), write own chunk
    #pragma unroll
    for (int i = 0; i < CH; ++i) a[i] = b1[ob + i];
    #pragma unroll 4
    for (int kb = 0; kb < 22; ++kb) {
        float4 v4 = hr[kb];
        #pragma unroll
        for (int j = 0; j < 4; ++j) {
            float v = ((const float*)&v4)[j];
            const float4* wq = (const float4*)(w1 + (kb * 4 + j) * HID + obv);
            float4 w0 = wq[0], w1v = wq[1];
            a[0] = fmaf(v, w0.x, a[0]);  a[1] = fmaf(v, w0.y, a[1]);
            a[2] = fmaf(v, w0.z, a[2]);  a[3] = fmaf(v, w0.w, a[3]);
            a[4] = fmaf(v, w1v.x, a[4]); a[5] = fmaf(v, w1v.y, a[5]);
            a[6] = fmaf(v, w1v.z, a[6]); a[7] = fmaf(v, w1v.w, a[7]);
        }
    }
    #pragma unroll
    for (int k = 88; k < SIN; ++k) {
        float v = H[lane * HST + k];
        const float* wr = w1 + k * HID + obv;
        #pragma unroll
        for (int i = 0; i < CH; ++i) a[i] = fmaf(v, wr[i], a[i]);
    }
    __syncthreads();                      // all x reads done
    #pragma unroll
    for (int i4 = 0; i4 < CH / 4; ++i4) {
        float4 w4;
        #pragma unroll
        for (int j = 0; j < 4; ++j) ((float*)&w4)[j] = fmaxf(a[i4 * 4 + j], 0.f);
        hw[i4] = w4;
    }
    __syncthreads();

    // ---- P2: enc h2 = relu(h1@w2 + b2)
    #pragma unroll
    for (int i = 0; i < CH; ++i) a[i] = b2[ob + i];
    #pragma unroll 4
    for (int kb = 0; kb < 32; ++kb) {
        float4 v4 = hr[kb];
        #pragma unroll
        for (int j = 0; j < 4; ++j) {
            float v = ((const float*)&v4)[j];
            const float4* wq = (const float4*)(w2 + (kb * 4 + j) * HID + obv);
            float4 w0 = wq[0], w1v = wq[1];
            a[0] = fmaf(v, w0.x, a[0]);  a[1] = fmaf(v, w0.y, a[1]);
            a[2] = fmaf(v, w0.z, a[2]);  a[3] = fmaf(v, w0.w, a[3]);
            a[4] = fmaf(v, w1v.x, a[4]); a[5] = fmaf(v, w1v.y, a[5]);
            a[6] = fmaf(v, w1v.z, a[6]); a[7] = fmaf(v, w1v.w, a[7]);
        }
    }
    __syncthreads();
    #pragma unroll
    for (int i4 = 0; i4 < CH / 4; ++i4) {
        float4 w4;
        #pragma unroll
        for (int j = 0; j < 4; ++j) ((float*)&w4)[j] = fmaxf(a[i4 * 4 + j], 0.f);
        hw[i4] = w4;
    }
    __syncthreads();

    // ---- P3 (fused): P = h2@WC + bfc; tq = Gm@h2 for ||rep||^2 partial
    {
        float tq[CH];
        #pragma unroll
        for (int i = 0; i < CH; ++i) { a[i] = bfc[ob + i]; tq[i] = 0.f; }
        #pragma unroll 2
        for (int kb = 0; kb < 32; ++kb) {
            float4 v4 = hr[kb];
            #pragma unroll
            for (int j = 0; j < 4; ++j) {
                float v = ((const float*)&v4)[j];
                const float4* wq = (const float4*)(WC + (kb * 4 + j) * NC + obv);
                const float4* gq = (const float4*)(Gm + (kb * 4 + j) * NC + obv);
                float4 w0 = wq[0], w1v = wq[1];
                float4 g0 = gq[0], g1v = gq[1];
                a[0] = fmaf(v, w0.x, a[0]);   a[1] = fmaf(v, w0.y, a[1]);
                a[2] = fmaf(v, w0.z, a[2]);   a[3] = fmaf(v, w0.w, a[3]);
                a[4] = fmaf(v, w1v.x, a[4]);  a[5] = fmaf(v, w1v.y, a[5]);
                a[6] = fmaf(v, w1v.z, a[6]);  a[7] = fmaf(v, w1v.w, a[7]);
                tq[0] = fmaf(v, g0.x, tq[0]);  tq[1] = fmaf(v, g0.y, tq[1]);
                tq[2] = fmaf(v, g0.z, tq[2]);  tq[3] = fmaf(v, g0.w, tq[3]);
                tq[4] = fmaf(v, g1v.x, tq[4]); tq[5] = fmaf(v, g1v.y, tq[5]);
                tq[6] = fmaf(v, g1v.z, tq[6]); tq[7] = fmaf(v, g1v.w, tq[7]);
            }
        }
        // own h2 chunk for the quadratic-form partial
        float part = 0.f;
        #pragma unroll
        for (int i4 = 0; i4 < CH / 4; ++i4) {
            float4 h4 = hr[ob / 4 + i4];
            #pragma unroll
            for (int j = 0; j < 4; ++j) {
                int i = i4 * 4 + j;
                part = fmaf(tq[i] + 2.f * uu[ob + i], ((const float*)&h4)[j], part);
            }
        }
        qfb[wv * 64 + lane] = part;
    }
    __syncthreads();                      // all h2 reads done
    #pragma unroll
    for (int i4 = 0; i4 < CH / 4; ++i4) {
        float4 w4;
        #pragma unroll
        for (int j = 0; j < 4; ++j) ((float*)&w4)[j] = a[i4 * 4 + j];
        hw[i4] = w4;
    }
    __syncthreads();

    // ---- P4: residual-VQ, 16 lanes per sample (all 16 waves active).
    //      Lane cl scores codes {cl, cl+16} (ascending -> strict < keeps first
    //      index); lexicographic (score,idx) min over 16 lanes preserves
    //      argmin first-index tie-break.
    {
        const int cl = lane & 15;
        const int sl = (wv << 2) + (lane >> 4);     // sample 0..63 in tile
        const float* Ps = H + sl * HST;

        float R = bb;
        #pragma unroll
        for (int w = 0; w < NW; ++w) R += qfb[w * 64 + sl];
        float vqp = 0.f;
        int k0, k1, k2, k3;

        // group 0
        {
            float rc0 = Ps[cl];
            float rc1 = Ps[cl + 16];
            float s0 = cbn2[cl] - 2.f * rc0;
            float s1 = cbn2[cl + 16] - 2.f * rc1;
            int   kb  = (s1 < s0) ? cl + 16 : cl;
            float sb  = (s1 < s0) ? s1 : s0;
            float rcb = (s1 < s0) ? rc1 : rc0;
            #pragma unroll
            for (int off = 1; off < 16; off <<= 1) {
                float so = __shfl_xor(sb, off);
                float ro = __shfl_xor(rcb, off);
                int   ko = __shfl_xor(kb, off);
                if (so < sb || (so == sb && ko < kb)) { sb = so; rcb = ro; kb = ko; }
            }
            k0 = kb;
            float dlt = cbn2[kb] - 2.f * rcb;
            vqp += R + dlt; R += dlt;
        }
        // group 1
        {
            const float* g01 = Gram + ((0 * 4 + 1) * 32 + k0) * 32;
            float rc0 = Ps[32 + cl] - g01[cl];
            float rc1 = Ps[32 + cl + 16] - g01[cl + 16];
            float s0 = cbn2[32 + cl] - 2.f * rc0;
            float s1 = cbn2[32 + cl + 16] - 2.f * rc1;
            int   kb  = (s1 < s0) ? cl + 16 : cl;
            float sb  = (s1 < s0) ? s1 : s0;
            float rcb = (s1 < s0) ? rc1 : rc0;
            #pragma unroll
            for (int off = 1; off < 16; off <<= 1) {
                float so = __shfl_xor(sb, off);
                float ro = __shfl_xor(rcb, off);
                int   ko = __shfl_xor(kb, off);
                if (so < sb || (so == sb && ko < kb)) { sb = so; rcb = ro; kb = ko; }
            }
            k1 = kb;
            float dlt = cbn2[32 + kb] - 2.f * rcb;
            vqp += R + dlt; R += dlt;
        }
        // group 2
        {
            const float* g02 = Gram + ((0 * 4 + 2) * 32 + k0) * 32;
            const float* g12 = Gram + ((1 * 4 + 2) * 32 + k1) * 32;
            float rc0 = Ps[64 + cl] - g02[cl] - g12[cl];
            float rc1 = Ps[64 + cl + 16] - g02[cl + 16] - g12[cl + 16];
            float s0 = cbn2[64 + cl] - 2.f * rc0;
            float s1 = cbn2[64 + cl + 16] - 2.f * rc1;
            int   kb  = (s1 < s0) ? cl + 16 : cl;
            float sb  = (s1 < s0) ? s1 : s0;
            float rcb = (s1 < s0) ? rc1 : rc0;
            #pragma unroll
            for (int off = 1; off < 16; off <<= 1) {
                float so = __shfl_xor(sb, off);
                float ro = __shfl_xor(rcb, off);
                int   ko = __shfl_xor(kb, off);
                if (so < sb || (so == sb && ko < kb)) { sb = so; rcb = ro; kb = ko; }
            }
            k2 = kb;
            float dlt = cbn2[64 + kb] - 2.f * rcb;
            vqp += R + dlt; R += dlt;
        }
        // group 3
        {
            const float* g03 = Gram + ((0 * 4 + 3) * 32 + k0) * 32;
            const float* g13 = Gram + ((1 * 4 + 3) * 32 + k1) * 32;
            const float* g23 = Gram + ((2 * 4 + 3) * 32 + k2) * 32;
            float rc0 = Ps[96 + cl] - g03[cl] - g13[cl] - g23[cl];
            float rc1 = Ps[96 + cl + 16] - g03[cl + 16] - g13[cl + 16] - g23[cl + 16];
            float s0 = cbn2[96 + cl] - 2.f * rc0;
            float s1 = cbn2[96 + cl + 16] - 2.f * rc1;
            int   kb  = (s1 < s0) ? cl + 16 : cl;
            float sb  = (s1 < s0) ? s1 : s0;
            float rcb = (s1 < s0) ? rc1 : rc0;
            #pragma unroll
            for (int off = 1; off < 16; off <<= 1) {
                float so = __shfl_xor(sb, off);
                float ro = __shfl_xor(rcb, off);
                int   ko = __shfl_xor(kb, off);
                if (so < sb || (so == sb && ko < kb)) { sb = so; rcb = ro; kb = ko; }
            }
            k3 = kb;
            float dlt = cbn2[96 + kb] - 2.f * rcb;
            vqp += R + dlt;
        }

        if (cl == 0) {
            cbuf[0 * 64 + sl] = k0; cbuf[1 * 64 + sl] = k1;
            cbuf[2 * 64 + sl] = k2; cbuf[3 * 64 + sl] = k3;
            float* op = out + 1 + ((long)blockIdx.x * 64 + sl) * 4;
            op[0] = (float)k0; op[1] = (float)k1; op[2] = (float)k2; op[3] = (float)k3;
        }
        float vs = (cl == 0) ? vqp : 0.f;
        #pragma unroll
        for (int off = 32; off > 0; off >>= 1) vs += __shfl_down(vs, off);
        if (lane == 0) red[2 * NW + wv] = vs;
    }
    __syncthreads();                      // P reads done; cbuf/red ready

    // ---- P5: dec h1 = relu(b1d + sum_g Mdec[g*32+k_g]); write own chunk
    {
        int cc0 = cbuf[lane], cc1 = cbuf[64 + lane], cc2 = cbuf[128 + lane], cc3 = cbuf[192 + lane];
        const float4* m0 = (const float4*)(Mdec + (0 * 32 + cc0) * HID + ob);
        const float4* m1 = (const float4*)(Mdec + (1 * 32 + cc1) * HID + ob);
        const float4* m2 = (const float4*)(Mdec + (2 * 32 + cc2) * HID + ob);
        const float4* m3 = (const float4*)(Mdec + (3 * 32 + cc3) * HID + ob);
        const float4* bd = (const float4*)(b1d + ob);
        #pragma unroll
        for (int i4 = 0; i4 < CH / 4; ++i4) {
            float4 v0 = m0[i4], v1 = m1[i4], v2 = m2[i4], v3 = m3[i4], vb = bd[i4];
            float4 w4;
            #pragma unroll
            for (int j = 0; j < 4; ++j) {
                float v = ((const float*)&vb)[j] + ((const float*)&v0)[j] + ((const float*)&v1)[j]
                        + ((const float*)&v2)[j] + ((const float*)&v3)[j];
                ((float*)&w4)[j] = fmaxf(v, 0.f);
            }
            hw[i4] = w4;
        }
    }
    __syncthreads();

    // ---- P6: dec h2 = relu(h@w2d + b2d)
    #pragma unroll
    for (int i = 0; i < CH; ++i) a[i] = b2d[ob + i];
    #pragma unroll 4
    for (int kb = 0; kb < 32; ++kb) {
        float4 v4 = hr[kb];
        #pragma unroll
        for (int j = 0; j < 4; ++j) {
            float v = ((const float*)&v4)[j];
            const float4* wq = (const float4*)(w2d + (kb * 4 + j) * HID + obv);
            float4 w0 = wq[0], w1v = wq[1];
            a[0] = fmaf(v, w0.x, a[0]);  a[1] = fmaf(v, w0.y, a[1]);
            a[2] = fmaf(v, w0.z, a[2]);  a[3] = fmaf(v, w0.w, a[3]);
            a[4] = fmaf(v, w1v.x, a[4]); a[5] = fmaf(v, w1v.y, a[5]);
            a[6] = fmaf(v, w1v.z, a[6]); a[7] = fmaf(v, w1v.w, a[7]);
        }
    }
    __syncthreads();
    #pragma unroll
    for (int i4 = 0; i4 < CH / 4; ++i4) {
        float4 w4;
        #pragma unroll
        for (int j = 0; j < 4; ++j) ((float*)&w4)[j] = fmaxf(a[i4 * 4 + j], 0.f);
        hw[i4] = w4;
    }
    __syncthreads();

    // ---- P7: dec out (90) + losses; wave wv covers o in [wv*6, wv*6+6) clamped
    float labs = 0.f, lsq = 0.f;
    {
        int o0v = wv * 6;
        asm volatile("" : "+v"(o0v));     // VGPR base -> VMEM weight loads
        const int o0 = wv * 6;
        float a7[6];
        #pragma unroll
        for (int i = 0; i < 6; ++i) { int oi = min(o0 + i, SIN - 1); a7[i] = bfd[oi]; }
        #pragma unroll 4
        for (int kb = 0; kb < 32; ++kb) {
            float4 v4 = hr[kb];
            #pragma unroll
            for (int j = 0; j < 4; ++j) {
                float v = ((const float*)&v4)[j];
                const float* wr = wfd + (kb * 4 + j) * SIN;
                #pragma unroll
                for (int i = 0; i < 6; ++i) {
                    int oi = min(o0v + i, SIN - 1);
                    a7[i] = fmaf(v, wr[oi], a7[i]);
                }
            }
        }
        const float* xr = x + ((long)blockIdx.x * 64 + lane) * SIN;
        #pragma unroll
        for (int i = 0; i < 6; ++i) {
            int o = o0 + i;
            if (o < SIN) {
                float e = a7[i] - xr[o];
                labs += fabsf(e);
                lsq  = fmaf(e, e, lsq);
            }
        }
    }
    #pragma unroll
    for (int off = 32; off > 0; off >>= 1) {
        labs += __shfl_down(labs, off);
        lsq  += __shfl_down(lsq, off);
    }
    if (lane == 0) { red[wv] = labs; red[NW + wv] = lsq; }
    __syncthreads();
    if (t == 0) {
        float A1 = 0.f, S1 = 0.f, V1 = 0.f;
        #pragma unroll
        for (int w = 0; w < NW; ++w) { A1 += red[w]; S1 += red[NW + w]; V1 += red[2 * NW + w]; }
        atomicAdd(acc + 0, (double)V1);
        atomicAdd(acc + 1, (double)A1);
        atomicAdd(acc + 2, (double)S1);
    }
}

__global__ void k_fin(const double* __restrict__ acc, float* __restrict__ out, int Bn) {
    if (threadIdx.x == 0 && blockIdx.x == 0) {
        double vq = acc[0] / ((double)Bn * (double)DLAT);
        double el = acc[1] / ((double)Bn * (double)SIN);
        double rc = acc[2] / ((double)Bn * (double)SIN);
        long co = 1 + (long)Bn * 4;
        out[0]      = (float)(el + 5.0 * vq);   // loss = encoder_loss*1 + vq_loss*5
        out[co]     = (float)vq;
        out[co + 1] = (float)rc;
        out[co + 2] = (float)el;
    }
}

extern "C" void kernel_launch(void* const* d_in, const int* in_sizes, int n_in,
                              void* d_out, int out_size, void* d_ws, size_t ws_size,
                              hipStream_t stream) {
    (void)n_in; (void)out_size; (void)ws_size;
    const float* x   = (const float*)d_in[0];
    const float* w1  = (const float*)d_in[1];
    const float* b1  = (const float*)d_in[2];
    const float* w2  = (const float*)d_in[3];
    const float* b2  = (const float*)d_in[4];
    const float* wf  = (const float*)d_in[5];
    const float* bf  = (const float*)d_in[6];
    const float* w1d = (const float*)d_in[7];
    const float* b1d = (const float*)d_in[8];
    const float* w2d = (const float*)d_in[9];
    const float* b2d = (const float*)d_in[10];
    const float* wfd = (const float*)d_in[11];
    const float* bfd = (const float*)d_in[12];
    const float* cb  = (const float*)d_in[13];

    float* out  = (float*)d_out;
    double* acc = (double*)d_ws;
    float* pre  = (float*)d_ws + 16;   // 64B offset, keeps doubles aligned

    int Bn = in_sizes[0] / SIN;

    hipLaunchKernelGGL(k_pre, dim3((PRE_N + 255) / 256), dim3(256), 0, stream,
                       wf, bf, w1d, cb, pre, acc);
    hipLaunchKernelGGL(k_main, dim3(Bn / 64), dim3(1024), 0, stream,
                       x, w1, b1, w2, b2, b1d, w2d, b2d, wfd, bfd, pre, out, acc, Bn);
    hipLaunchKernelGGL(k_fin, dim3(1), dim3(64), 0, stream, acc, out, Bn);
}

// Round 14
// 521.379 us; speedup vs baseline: 2.7953x; 2.7953x over previous
//
#include <hip/hip_runtime.h>

// VQ-VAE fused forward, f32 throughout.
// Algebra: all 512-dim contractions folded into precomputed tables:
//   WC[k][c]  = enc_wf[k,:]·cb[c,:]          (P = rep·cb^T = h2@WC + bfc)
//   Gm[o][k]  = enc_wf[o,:]·enc_wf[k,:]      (||rep||^2 = h2^T Gm h2 + 2 u·h2 + bb)
//   Mdec[r][j]= cb[r,:]·dec_w1[:,j]          (dec h1 preact = b1d + sum_g Mdec[g*32+k_g])
//   Gram[ga,gb,ka,kb] = cb_ga[ka,:]·cb_gb[kb,:]  (residual dots across groups)
// R13 (resubmit; bench never ran - GPU acquisition timeout):
// Model: R4(occ 89%)≈R8(occ 41%) both ~52% VALU at the SAME FMA-per-SMEM-
// request ratio (8 FMA/req) -> per-CU scalar-memory REQUEST RATE saturates.
// Fix: halve requests — load each CH=16 weight chunk as ONE 64B f32x16 from
// the wave-uniform 64B-aligned address; compiler emits s_load_dwordx16 with
// counted lgkmcnt (16 FMA/req). Worst case 2x dwordx8 = R8 reproduction.
// Base = R8-measured kernel (512 thr, 8 waves x CH=16, 37KB LDS, VGPR 48,
// no spill) + R9's 4-chain-ILP k_pre.

#define SIN  90
#define HID  128
#define DLAT 512
#define NC   128
#define HST  132    // H row stride (dwords): %4==0 (b128 align), %32==4 (bank spread)

// ws float layout, after 8 doubles (64 bytes) of accumulators:
//   [0,16384)      WC
//   [16384,32768)  Gm
//   [32768,49152)  Mdec  (row = g*32+k, col j)
//   [49152,65536)  Gram  idx = ((ga*4+gb)*32+ka)*32+kb
//   [65536,65664)  cbn2[128]
//   [65664,65792)  u[128]      (wf·bf)
//   [65792,65920)  bfc[128]    (bf·cb_c)
//   [65920]        bb = ||bf||^2
#define PRE_N 65921

typedef __attribute__((ext_vector_type(16))) float f32x16;

__device__ __forceinline__ float dot512(const float* __restrict__ a,
                                        const float* __restrict__ b) {
    const float4* a4 = (const float4*)a;
    const float4* b4 = (const float4*)b;
    float s0 = 0.f, s1 = 0.f, s2 = 0.f, s3 = 0.f;
    for (int d = 0; d < DLAT / 4; d += 4) {
        float4 av, bv;
        av = a4[d];     bv = b4[d];
        s0 = fmaf(av.x, bv.x, s0); s0 = fmaf(av.y, bv.y, s0);
        s0 = fmaf(av.z, bv.z, s0); s0 = fmaf(av.w, bv.w, s0);
        av = a4[d + 1]; bv = b4[d + 1];
        s1 = fmaf(av.x, bv.x, s1); s1 = fmaf(av.y, bv.y, s1);
        s1 = fmaf(av.z, bv.z, s1); s1 = fmaf(av.w, bv.w, s1);
        av = a4[d + 2]; bv = b4[d + 2];
        s2 = fmaf(av.x, bv.x, s2); s2 = fmaf(av.y, bv.y, s2);
        s2 = fmaf(av.z, bv.z, s2); s2 = fmaf(av.w, bv.w, s2);
        av = a4[d + 3]; bv = b4[d + 3];
        s3 = fmaf(av.x, bv.x, s3); s3 = fmaf(av.y, bv.y, s3);
        s3 = fmaf(av.z, bv.z, s3); s3 = fmaf(av.w, bv.w, s3);
    }
    return (s0 + s1) + (s2 + s3);
}

__global__ void k_pre(const float* __restrict__ wf, const float* __restrict__ bf,
                      const float* __restrict__ w1d, const float* __restrict__ cb,
                      float* __restrict__ P, double* __restrict__ acc) {
    int idx = blockIdx.x * 256 + threadIdx.x;
    if (idx < 4) acc[idx] = 0.0;          // folded k_zero
    if (idx >= PRE_N) return;
    float s = 0.f;
    if (idx < 16384) {
        int k = idx >> 7, c = idx & 127;
        s = dot512(wf + k * DLAT, cb + c * DLAT);
    } else if (idx < 32768) {
        int r = idx - 16384; int o = r >> 7, k = r & 127;
        s = dot512(wf + o * DLAT, wf + k * DLAT);
    } else if (idx < 49152) {
        int r = idx - 32768; int row = r >> 7, j = r & 127;
        const float* a = cb + row * DLAT;
        float t0 = 0.f, t1 = 0.f;
        for (int d = 0; d < DLAT; d += 2) {
            t0 = fmaf(a[d],     w1d[d * HID + j],       t0);
            t1 = fmaf(a[d + 1], w1d[(d + 1) * HID + j], t1);
        }
        s = t0 + t1;
    } else if (idx < 65536) {
        int r = idx - 49152;
        int kb = r & 31, ka = (r >> 5) & 31, gb = (r >> 10) & 3, ga = (r >> 12) & 3;
        s = dot512(cb + (ga * 32 + ka) * DLAT, cb + (gb * 32 + kb) * DLAT);
    } else if (idx < 65664) {
        int c = idx - 65536;
        s = dot512(cb + c * DLAT, cb + c * DLAT);
    } else if (idx < 65792) {
        int k = idx - 65664;
        s = dot512(wf + k * DLAT, bf);
    } else if (idx < 65920) {
        int c = idx - 65792;
        s = dot512(bf, cb + c * DLAT);
    } else {
        s = dot512(bf, bf);
    }
    P[idx] = s;
}

#define CH 16     // out dims per wave (8 waves x 16 = 128)
#define NW 8      // waves per block

__global__ __launch_bounds__(512, 4) void k_main(
    const float* __restrict__ x,
    const float* __restrict__ w1, const float* __restrict__ b1,
    const float* __restrict__ w2, const float* __restrict__ b2,
    const float* __restrict__ b1d,
    const float* __restrict__ w2d, const float* __restrict__ b2d,
    const float* __restrict__ wfd, const float* __restrict__ bfd,
    const float* __restrict__ pre,
    float* __restrict__ out, double* __restrict__ acc, int Bn)
{
    __shared__ __align__(16) float H[64 * HST];
    __shared__ float qfb[NW * 64];
    __shared__ int   cbuf[4 * 64];
    __shared__ float red[3 * NW];

    const int t = threadIdx.x;
    const int lane = t & 63;
    const int wv = t >> 6;                                    // 0..7
    const int ob = __builtin_amdgcn_readfirstlane(wv) * CH;   // wave-uniform chunk base

    const float* WC   = pre;
    const float* Gm   = pre + 16384;
    const float* Mdec = pre + 32768;
    const float* Gram = pre + 49152;
    const float* cbn2 = pre + 65536;
    const float* uu   = pre + 65664;
    const float* bfc  = pre + 65792;
    const float  bb   = pre[65920];

    const float4* hr = (const float4*)(H + lane * HST);   // own row, b128 stream
    float4*       hw = (float4*)(H + lane * HST + ob);    // own row, own chunk

    float a[CH];

    // ---- P0: stage x tile -> H[s][0..89] (coalesced global reads)
    {
        const float* xb = x + (long)blockIdx.x * 64 * SIN;
        for (int i = t; i < 64 * SIN; i += 512) {
            int s = i / SIN;
            int k = i - s * SIN;
            H[s * HST + k] = xb[i];
        }
    }
    __syncthreads();

    // ---- P1: enc h1 = relu(x@w1 + b1); read own row (x), write own chunk
    #pragma unroll
    for (int i = 0; i < CH; ++i) a[i] = b1[ob + i];
    #pragma unroll 2
    for (int kb = 0; kb < 22; ++kb) {
        float4 v4 = hr[kb];
        #pragma unroll
        for (int j = 0; j < 4; ++j) {
            float v = ((const float*)&v4)[j];
            f32x16 wrow = *(const f32x16*)(w1 + (kb * 4 + j) * HID + ob);
            #pragma unroll
            for (int i = 0; i < CH; ++i) a[i] = fmaf(v, wrow[i], a[i]);
        }
    }
    #pragma unroll
    for (int k = 88; k < SIN; ++k) {
        float v = H[lane * HST + k];
        f32x16 wrow = *(const f32x16*)(w1 + k * HID + ob);
        #pragma unroll
        for (int i = 0; i < CH; ++i) a[i] = fmaf(v, wrow[i], a[i]);
    }
    __syncthreads();                      // all x reads done
    #pragma unroll
    for (int i4 = 0; i4 < CH / 4; ++i4) {
        float4 w4;
        #pragma unroll
        for (int j = 0; j < 4; ++j) ((float*)&w4)[j] = fmaxf(a[i4 * 4 + j], 0.f);
        hw[i4] = w4;
    }
    __syncthreads();

    // ---- P2: enc h2 = relu(h1@w2 + b2)
    #pragma unroll
    for (int i = 0; i < CH; ++i) a[i] = b2[ob + i];
    #pragma unroll 2
    for (int kb = 0; kb < 32; ++kb) {
        float4 v4 = hr[kb];
        #pragma unroll
        for (int j = 0; j < 4; ++j) {
            float v = ((const float*)&v4)[j];
            f32x16 wrow = *(const f32x16*)(w2 + (kb * 4 + j) * HID + ob);
            #pragma unroll
            for (int i = 0; i < CH; ++i) a[i] = fmaf(v, wrow[i], a[i]);
        }
    }
    __syncthreads();
    #pragma unroll
    for (int i4 = 0; i4 < CH / 4; ++i4) {
        float4 w4;
        #pragma unroll
        for (int j = 0; j < 4; ++j) ((float*)&w4)[j] = fmaxf(a[i4 * 4 + j], 0.f);
        hw[i4] = w4;
    }
    __syncthreads();

    // ---- P3 (fused): P = h2@WC + bfc; tq = Gm@h2 for ||rep||^2 partial
    {
        float tq[CH];
        #pragma unroll
        for (int i = 0; i < CH; ++i) { a[i] = bfc[ob + i]; tq[i] = 0.f; }
        for (int kb = 0; kb < 32; ++kb) {
            float4 v4 = hr[kb];
            #pragma unroll
            for (int j = 0; j < 4; ++j) {
                float v = ((const float*)&v4)[j];
                f32x16 wrow = *(const f32x16*)(WC + (kb * 4 + j) * NC + ob);
                #pragma unroll
                for (int i = 0; i < CH; ++i) a[i] = fmaf(v, wrow[i], a[i]);
                f32x16 grow = *(const f32x16*)(Gm + (kb * 4 + j) * NC + ob);
                #pragma unroll
                for (int i = 0; i < CH; ++i) tq[i] = fmaf(v, grow[i], tq[i]);
            }
        }
        // own h2 chunk for the quadratic-form partial
        float part = 0.f;
        #pragma unroll
        for (int i4 = 0; i4 < CH / 4; ++i4) {
            float4 h4 = hr[ob / 4 + i4];
            #pragma unroll
            for (int j = 0; j < 4; ++j) {
                int i = i4 * 4 + j;
                part = fmaf(tq[i] + 2.f * uu[ob + i], ((const float*)&h4)[j], part);
            }
        }
        qfb[wv * 64 + lane] = part;
    }
    __syncthreads();                      // all h2 reads done
    #pragma unroll
    for (int i4 = 0; i4 < CH / 4; ++i4) {
        float4 w4;
        #pragma unroll
        for (int j = 0; j < 4; ++j) ((float*)&w4)[j] = a[i4 * 4 + j];
        hw[i4] = w4;
    }
    __syncthreads();

    // ---- P4: residual-VQ, 8 lanes per sample (all 8 waves active).
    //      Lane cl scores codes {cl, cl+8, cl+16, cl+24} (ascending -> strict <
    //      keeps first index); lexicographic (score,idx) min over 8 lanes
    //      preserves argmin first-index tie-break.
    {
        const int cl = lane & 7;
        const int sl = (wv << 3) + (lane >> 3);     // sample 0..63 in tile
        const float* Ps = H + sl * HST;

        float R = bb;
        #pragma unroll
        for (int w = 0; w < NW; ++w) R += qfb[w * 64 + sl];
        float vqp = 0.f;
        int k0, k1, k2, k3;

        // group 0
        {
            float sb = 1e30f, rcb = 0.f; int kb = 0;
            #pragma unroll
            for (int q = 0; q < 4; ++q) {
                int c = cl + (q << 3);
                float rc = Ps[c];
                float sc = cbn2[c] - 2.f * rc;
                if (sc < sb) { sb = sc; kb = c; rcb = rc; }
            }
            #pragma unroll
            for (int off = 1; off < 8; off <<= 1) {
                float so = __shfl_xor(sb, off);
                float ro = __shfl_xor(rcb, off);
                int   ko = __shfl_xor(kb, off);
                if (so < sb || (so == sb && ko < kb)) { sb = so; rcb = ro; kb = ko; }
            }
            k0 = kb;
            float dlt = cbn2[kb] - 2.f * rcb;
            vqp += R + dlt; R += dlt;
        }
        // group 1
        {
            const float* g01 = Gram + ((0 * 4 + 1) * 32 + k0) * 32;
            float sb = 1e30f, rcb = 0.f; int kb = 0;
            #pragma unroll
            for (int q = 0; q < 4; ++q) {
                int c = cl + (q << 3);
                float rc = Ps[32 + c] - g01[c];
                float sc = cbn2[32 + c] - 2.f * rc;
                if (sc < sb) { sb = sc; kb = c; rcb = rc; }
            }
            #pragma unroll
            for (int off = 1; off < 8; off <<= 1) {
                float so = __shfl_xor(sb, off);
                float ro = __shfl_xor(rcb, off);
                int   ko = __shfl_xor(kb, off);
                if (so < sb || (so == sb && ko < kb)) { sb = so; rcb = ro; kb = ko; }
            }
            k1 = kb;
            float dlt = cbn2[32 + kb] - 2.f * rcb;
            vqp += R + dlt; R += dlt;
        }
        // group 2
        {
            const float* g02 = Gram + ((0 * 4 + 2) * 32 + k0) * 32;
            const float* g12 = Gram + ((1 * 4 + 2) * 32 + k1) * 32;
            float sb = 1e30f, rcb = 0.f; int kb = 0;
            #pragma unroll
            for (int q = 0; q < 4; ++q) {
                int c = cl + (q << 3);
                float rc = Ps[64 + c] - g02[c] - g12[c];
                float sc = cbn2[64 + c] - 2.f * rc;
                if (sc < sb) { sb = sc; kb = c; rcb = rc; }
            }
            #pragma unroll
            for (int off = 1; off < 8; off <<= 1) {
                float so = __shfl_xor(sb, off);
                float ro = __shfl_xor(rcb, off);
                int   ko = __shfl_xor(kb, off);
                if (so < sb || (so == sb && ko < kb)) { sb = so; rcb = ro; kb = ko; }
            }
            k2 = kb;
            float dlt = cbn2[64 + kb] - 2.f * rcb;
            vqp += R + dlt; R += dlt;
        }
        // group 3
        {
            const float* g03 = Gram + ((0 * 4 + 3) * 32 + k0) * 32;
            const float* g13 = Gram + ((1 * 4 + 3) * 32 + k1) * 32;
            const float* g23 = Gram + ((2 * 4 + 3) * 32 + k2) * 32;
            float sb = 1e30f, rcb = 0.f; int kb = 0;
            #pragma unroll
            for (int q = 0; q < 4; ++q) {
                int c = cl + (q << 3);
                float rc = Ps[96 + c] - g03[c] - g13[c] - g23[c];
                float sc = cbn2[96 + c] - 2.f * rc;
                if (sc < sb) { sb = sc; kb = c; rcb = rc; }
            }
            #pragma unroll
            for (int off = 1; off < 8; off <<= 1) {
                float so = __shfl_xor(sb, off);
                float ro = __shfl_xor(rcb, off);
                int   ko = __shfl_xor(kb, off);
                if (so < sb || (so == sb && ko < kb)) { sb = so; rcb = ro; kb = ko; }
            }
            k3 = kb;
            float dlt = cbn2[96 + kb] - 2.f * rcb;
            vqp += R + dlt;
        }

        if (cl == 0) {
            cbuf[0 * 64 + sl] = k0; cbuf[1 * 64 + sl] = k1;
            cbuf[2 * 64 + sl] = k2; cbuf[3 * 64 + sl] = k3;
            float* op = out + 1 + ((long)blockIdx.x * 64 + sl) * 4;
            op[0] = (float)k0; op[1] = (float)k1; op[2] = (float)k2; op[3] = (float)k3;
        }
        float vs = (cl == 0) ? vqp : 0.f;
        #pragma unroll
        for (int off = 32; off > 0; off >>= 1) vs += __shfl_down(vs, off);
        if (lane == 0) red[2 * NW + wv] = vs;
    }
    __syncthreads();                      // P reads done; cbuf/red ready

    // ---- P5: dec h1 = relu(b1d + sum_g Mdec[g*32+k_g]); write own chunk
    {
        int cc0 = cbuf[lane], cc1 = cbuf[64 + lane], cc2 = cbuf[128 + lane], cc3 = cbuf[192 + lane];
        const float4* m0 = (const float4*)(Mdec + (0 * 32 + cc0) * HID + ob);
        const float4* m1 = (const float4*)(Mdec + (1 * 32 + cc1) * HID + ob);
        const float4* m2 = (const float4*)(Mdec + (2 * 32 + cc2) * HID + ob);
        const float4* m3 = (const float4*)(Mdec + (3 * 32 + cc3) * HID + ob);
        const float4* bd = (const float4*)(b1d + ob);
        #pragma unroll
        for (int i4 = 0; i4 < CH / 4; ++i4) {
            float4 v0 = m0[i4], v1 = m1[i4], v2 = m2[i4], v3 = m3[i4], vb = bd[i4];
            float4 w4;
            #pragma unroll
            for (int j = 0; j < 4; ++j) {
                float v = ((const float*)&vb)[j] + ((const float*)&v0)[j] + ((const float*)&v1)[j]
                        + ((const float*)&v2)[j] + ((const float*)&v3)[j];
                ((float*)&w4)[j] = fmaxf(v, 0.f);
            }
            hw[i4] = w4;
        }
    }
    __syncthreads();

    // ---- P6: dec h2 = relu(h@w2d + b2d)
    #pragma unroll
    for (int i = 0; i < CH; ++i) a[i] = b2d[ob + i];
    #pragma unroll 2
    for (int kb = 0; kb < 32; ++kb) {
        float4 v4 = hr[kb];
        #pragma unroll
        for (int j = 0; j < 4; ++j) {
            float v = ((const float*)&v4)[j];
            f32x16 wrow = *(const f32x16*)(w2d + (kb * 4 + j) * HID + ob);
            #pragma unroll
            for (int i = 0; i < CH; ++i) a[i] = fmaf(v, wrow[i], a[i]);
        }
    }
    __syncthreads();
    #pragma unroll
    for (int i4 = 0; i4 < CH / 4; ++i4) {
        float4 w4;
        #pragma unroll
        for (int j = 0; j < 4; ++j) ((float*)&w4)[j] = fmaxf(a[i4 * 4 + j], 0.f);
        hw[i4] = w4;
    }
    __syncthreads();

    // ---- P7: dec out (90) + losses; wave wv covers o in [wv*12, wv*12+12) clamped
    float labs = 0.f, lsq = 0.f;
    {
        const int o0 = wv * 12;
        float a7[12];
        #pragma unroll
        for (int i = 0; i < 12; ++i) { int oi = min(o0 + i, SIN - 1); a7[i] = bfd[oi]; }
        #pragma unroll 4
        for (int kb = 0; kb < 32; ++kb) {
            float4 v4 = hr[kb];
            #pragma unroll
            for (int j = 0; j < 4; ++j) {
                float v = ((const float*)&v4)[j];
                const float* wr = wfd + (kb * 4 + j) * SIN;
                #pragma unroll
                for (int i = 0; i < 12; ++i) {
                    int oi = min(o0 + i, SIN - 1);
                    a7[i] = fmaf(v, wr[oi], a7[i]);
                }
            }
        }
        const float* xr = x + ((long)blockIdx.x * 64 + lane) * SIN;
        #pragma unroll
        for (int i = 0; i < 12; ++i) {
            int o = o0 + i;
            if (o < SIN) {
                float e = a7[i] - xr[o];
                labs += fabsf(e);
                lsq  = fmaf(e, e, lsq);
            }
        }
    }
    #pragma unroll
    for (int off = 32; off > 0; off >>= 1) {
        labs += __shfl_down(labs, off);
        lsq  += __shfl_down(lsq, off);
    }
    if (lane == 0) { red[wv] = labs; red[NW + wv] = lsq; }
    __syncthreads();
    if (t == 0) {
        float A1 = 0.f, S1 = 0.f, V1 = 0.f;
        #pragma unroll
        for (int w = 0; w < NW; ++w) { A1 += red[w]; S1 += red[NW + w]; V1 += red[2 * NW + w]; }
        atomicAdd(acc + 0, (double)V1);
        atomicAdd(acc + 1, (double)A1);
        atomicAdd(acc + 2, (double)S1);
    }
}

__global__ void k_fin(const double* __restrict__ acc, float* __restrict__ out, int Bn) {
    if (threadIdx.x == 0 && blockIdx.x == 0) {
        double vq = acc[0] / ((double)Bn * (double)DLAT);
        double el = acc[1] / ((double)Bn * (double)SIN);
        double rc = acc[2] / ((double)Bn * (double)SIN);
        long co = 1 + (long)Bn * 4;
        out[0]      = (float)(el + 5.0 * vq);   // loss = encoder_loss*1 + vq_loss*5
        out[co]     = (float)vq;
        out[co + 1] = (float)rc;
        out[co + 2] = (float)el;
    }
}

extern "C" void kernel_launch(void* const* d_in, const int* in_sizes, int n_in,
                              void* d_out, int out_size, void* d_ws, size_t ws_size,
                              hipStream_t stream) {
    (void)n_in; (void)out_size; (void)ws_size;
    const float* x   = (const float*)d_in[0];
    const float* w1  = (const float*)d_in[1];
    const float* b1  = (const float*)d_in[2];
    const float* w2  = (const float*)d_in[3];
    const float* b2  = (const float*)d_in[4];
    const float* wf  = (const float*)d_in[5];
    const float* bf  = (const float*)d_in[6];
    const float* w1d = (const float*)d_in[7];
    const float* b1d = (const float*)d_in[8];
    const float* w2d = (const float*)d_in[9];
    const float* b2d = (const float*)d_in[10];
    const float* wfd = (const float*)d_in[11];
    const float* bfd = (const float*)d_in[12];
    const float* cb  = (const float*)d_in[13];

    float* out  = (float*)d_out;
    double* acc = (double*)d_ws;
    float* pre  = (float*)d_ws + 16;   // 64B offset, keeps doubles aligned

    int Bn = in_sizes[0] / SIN;

    hipLaunchKernelGGL(k_pre, dim3((PRE_N + 255) / 256), dim3(256), 0, stream,
                       wf, bf, w1d, cb, pre, acc);
    hipLaunchKernelGGL(k_main, dim3(Bn / 64), dim3(512), 0, stream,
                       x, w1, b1, w2, b2, b1d, w2d, b2d, wfd, bfd, pre, out, acc, Bn);
    hipLaunchKernelGGL(k_fin, dim3(1), dim3(64), 0, stream, acc, out, Bn);
}